// Round 1
// baseline (648.256 us; speedup 1.0000x reference)
//
#include <hip/hip_runtime.h>
#include <hip/hip_bf16.h>
#include <math.h>

// Problem constants
#define NB   2
#define LSEQ 384
#define DMODEL 512
#define NH   8
#define HD2  64
#define DMLP 2048
#define LL2  (LSEQ*LSEQ)          // 147456
#define ROWS (NB*LSEQ)            // 768

// ---------------------------------------------------------------------------
// allpad[n] = all(mask[n, :])
__global__ void allpad_kernel(const int* __restrict__ mask, int* __restrict__ allpad) {
    int n = threadIdx.x >> 6, lane = threadIdx.x & 63;
    if (n < NB) {
        int pad = 1;
        for (int j = lane; j < LSEQ; j += 64) pad &= (mask[n * LSEQ + j] != 0) ? 1 : 0;
        unsigned long long bal = __ballot(pad != 0);
        if (lane == 0) allpad[n] = (bal == 0xFFFFFFFFFFFFFFFFull) ? 1 : 0;
    }
}

// ---------------------------------------------------------------------------
// LayerNorm: one wave per 512-elem row, 4 rows per block
__global__ __launch_bounds__(256) void ln_kernel(const float* __restrict__ src,
                                                 const float* __restrict__ g,
                                                 const float* __restrict__ b,
                                                 float* __restrict__ dst) {
    int lane = threadIdx.x & 63;
    int row  = blockIdx.x * 4 + (threadIdx.x >> 6);
    const float* p = src + (size_t)row * DMODEL + lane * 8;
    float4 v0 = *(const float4*)p;
    float4 v1 = *(const float4*)(p + 4);
    float s  = v0.x + v0.y + v0.z + v0.w + v1.x + v1.y + v1.z + v1.w;
    float ss = v0.x*v0.x + v0.y*v0.y + v0.z*v0.z + v0.w*v0.w
             + v1.x*v1.x + v1.y*v1.y + v1.z*v1.z + v1.w*v1.w;
    #pragma unroll
    for (int o = 32; o; o >>= 1) { s += __shfl_xor(s, o); ss += __shfl_xor(ss, o); }
    float m   = s * (1.0f / DMODEL);
    float var = ss * (1.0f / DMODEL) - m * m;
    float r   = rsqrtf(var + 1e-5f);
    float4 g0 = *(const float4*)(g + lane * 8);
    float4 g1 = *(const float4*)(g + lane * 8 + 4);
    float4 b0 = *(const float4*)(b + lane * 8);
    float4 b1 = *(const float4*)(b + lane * 8 + 4);
    float4 o0, o1;
    o0.x = (v0.x - m) * r * g0.x + b0.x;
    o0.y = (v0.y - m) * r * g0.y + b0.y;
    o0.z = (v0.z - m) * r * g0.z + b0.z;
    o0.w = (v0.w - m) * r * g0.w + b0.w;
    o1.x = (v1.x - m) * r * g1.x + b1.x;
    o1.y = (v1.y - m) * r * g1.y + b1.y;
    o1.z = (v1.z - m) * r * g1.z + b1.z;
    o1.w = (v1.w - m) * r * g1.w + b1.w;
    float* q = dst + (size_t)row * DMODEL + lane * 8;
    *(float4*)q = o0;
    *(float4*)(q + 4) = o1;
}

// ---------------------------------------------------------------------------
// bias[n][h][i][j] = pd[n,i,j,:] . edw[h,:] + edb[h]
// one wave per (n,i,j) row of 512; edw held in registers (lane owns 8 elems)
__global__ __launch_bounds__(256) void bias_kernel(const float* __restrict__ pd,
                                                   const float* __restrict__ edw,
                                                   const float* __restrict__ edb,
                                                   float* __restrict__ biasb) {
    const int lane = threadIdx.x & 63;
    const int wid  = blockIdx.x * 4 + (threadIdx.x >> 6);
    const int nw   = gridDim.x * 4;
    float w[8][8];
    #pragma unroll
    for (int h = 0; h < 8; h++) {
        float4 aa = *(const float4*)&edw[h * DMODEL + lane * 8];
        float4 bb = *(const float4*)&edw[h * DMODEL + lane * 8 + 4];
        w[h][0]=aa.x; w[h][1]=aa.y; w[h][2]=aa.z; w[h][3]=aa.w;
        w[h][4]=bb.x; w[h][5]=bb.y; w[h][6]=bb.z; w[h][7]=bb.w;
    }
    float eb[8];
    #pragma unroll
    for (int h = 0; h < 8; h++) eb[h] = edb[h];

    const int total = NB * LL2; // 294912
    for (int row = wid; row < total; row += nw) {
        const float* src = pd + (size_t)row * DMODEL + lane * 8;
        float4 d0 = *(const float4*)src;
        float4 d1 = *(const float4*)(src + 4);
        float acc[8];
        #pragma unroll
        for (int h = 0; h < 8; h++) {
            acc[h] = d0.x*w[h][0] + d0.y*w[h][1] + d0.z*w[h][2] + d0.w*w[h][3]
                   + d1.x*w[h][4] + d1.y*w[h][5] + d1.z*w[h][6] + d1.w*w[h][7];
        }
        #pragma unroll
        for (int o = 32; o; o >>= 1) {
            #pragma unroll
            for (int h = 0; h < 8; h++) acc[h] += __shfl_xor(acc[h], o);
        }
        if (lane == 0) {
            int nidx = row / LL2;
            int ij   = row - nidx * LL2;
            size_t base = (size_t)nidx * 8 * LL2 + ij;
            #pragma unroll
            for (int h = 0; h < 8; h++) biasb[base + (size_t)h * LL2] = acc[h] + eb[h];
        }
    }
}

// ---------------------------------------------------------------------------
// Generic f32 GEMM: C[M,Nn] = op(A[M,K] @ W[Nn,K]^T + bv) (+ Rsd)
// 64x64 tile, 256 threads, 4x4 per thread, K-step 16
template<int ACT, int RES>
__global__ __launch_bounds__(256) void gemm_kernel(const float* __restrict__ A,
                                                   const float* __restrict__ W,
                                                   const float* __restrict__ bv,
                                                   const float* __restrict__ Rsd,
                                                   float* __restrict__ C,
                                                   int M, int Nn, int K) {
    __shared__ float As[16][64];
    __shared__ float Ws[16][64];
    const int tid = threadIdx.x;
    const int tx = tid & 15, ty = tid >> 4;
    const int m0 = blockIdx.y * 64, n0 = blockIdx.x * 64;
    const int ar = tid >> 2, ak = (tid & 3) << 2;
    float acc[4][4];
    #pragma unroll
    for (int i = 0; i < 4; i++)
        #pragma unroll
        for (int j = 0; j < 4; j++) acc[i][j] = 0.0f;

    for (int k0 = 0; k0 < K; k0 += 16) {
        float4 av = *(const float4*)&A[(size_t)(m0 + ar) * K + k0 + ak];
        float4 wv = *(const float4*)&W[(size_t)(n0 + ar) * K + k0 + ak];
        As[ak+0][ar]=av.x; As[ak+1][ar]=av.y; As[ak+2][ar]=av.z; As[ak+3][ar]=av.w;
        Ws[ak+0][ar]=wv.x; Ws[ak+1][ar]=wv.y; Ws[ak+2][ar]=wv.z; Ws[ak+3][ar]=wv.w;
        __syncthreads();
        #pragma unroll
        for (int k = 0; k < 16; k++) {
            float4 a4 = *(const float4*)&As[k][ty << 2];
            float4 w4 = *(const float4*)&Ws[k][tx << 2];
            float a[4] = {a4.x, a4.y, a4.z, a4.w};
            float w[4] = {w4.x, w4.y, w4.z, w4.w};
            #pragma unroll
            for (int i = 0; i < 4; i++)
                #pragma unroll
                for (int j = 0; j < 4; j++) acc[i][j] = fmaf(a[i], w[j], acc[i][j]);
        }
        __syncthreads();
    }

    float4 bb = *(const float4*)&bv[n0 + (tx << 2)];
    #pragma unroll
    for (int i = 0; i < 4; i++) {
        int row = m0 + (ty << 2) + i;
        float o[4] = {acc[i][0] + bb.x, acc[i][1] + bb.y, acc[i][2] + bb.z, acc[i][3] + bb.w};
        if (ACT == 1) {
            #pragma unroll
            for (int j = 0; j < 4; j++) o[j] = o[j] / (1.0f + expf(-o[j]));
        }
        if (RES == 1) {
            float4 rr = *(const float4*)&Rsd[(size_t)row * Nn + n0 + (tx << 2)];
            o[0] += rr.x; o[1] += rr.y; o[2] += rr.z; o[3] += rr.w;
        }
        float4 ov = {o[0], o[1], o[2], o[3]};
        *(float4*)&C[(size_t)row * Nn + n0 + (tx << 2)] = ov;
    }
}

// ---------------------------------------------------------------------------
// scores[n,h,i,j] = 0.125 * q_i.k_j + bias[n,h,i,j] + mask
// block = (it*12+jt, h, n); 32x32 output tile; K=64 fully staged
__global__ __launch_bounds__(256) void scores_kernel(const float* __restrict__ q,
                                                     const float* __restrict__ kv,
                                                     const float* __restrict__ biasb,
                                                     const int* __restrict__ mask,
                                                     const int* __restrict__ allpad,
                                                     float* __restrict__ S) {
    const int n = blockIdx.z, h = blockIdx.y;
    const int it = blockIdx.x / 12, jt = blockIdx.x % 12;
    __shared__ float Qs[64][32];
    __shared__ float Ks[64][32];
    const int tid = threadIdx.x;
    const int r = tid >> 3, c = (tid & 7) << 3;
    {
        const float* qp = q + ((size_t)(n * LSEQ + it * 32 + r)) * DMODEL + h * HD2 + c;
        float4 q0 = *(const float4*)qp;
        float4 q1 = *(const float4*)(qp + 4);
        Qs[c+0][r]=q0.x; Qs[c+1][r]=q0.y; Qs[c+2][r]=q0.z; Qs[c+3][r]=q0.w;
        Qs[c+4][r]=q1.x; Qs[c+5][r]=q1.y; Qs[c+6][r]=q1.z; Qs[c+7][r]=q1.w;
        const float* kp = kv + ((size_t)(n * LSEQ + jt * 32 + r)) * (2 * DMODEL) + h * HD2 + c;
        float4 k0 = *(const float4*)kp;
        float4 k1 = *(const float4*)(kp + 4);
        Ks[c+0][r]=k0.x; Ks[c+1][r]=k0.y; Ks[c+2][r]=k0.z; Ks[c+3][r]=k0.w;
        Ks[c+4][r]=k1.x; Ks[c+5][r]=k1.y; Ks[c+6][r]=k1.z; Ks[c+7][r]=k1.w;
    }
    __syncthreads();
    const int tx = tid & 15, ty = tid >> 4;
    float acc[2][2] = {{0.f,0.f},{0.f,0.f}};
    #pragma unroll
    for (int k = 0; k < 64; k++) {
        float2 a  = *(const float2*)&Qs[k][ty << 1];
        float2 b2 = *(const float2*)&Ks[k][tx << 1];
        acc[0][0] = fmaf(a.x, b2.x, acc[0][0]);
        acc[0][1] = fmaf(a.x, b2.y, acc[0][1]);
        acc[1][0] = fmaf(a.y, b2.x, acc[1][0]);
        acc[1][1] = fmaf(a.y, b2.y, acc[1][1]);
    }
    const int ap = allpad[n];
    const float NEGINF = -__builtin_inff();
    #pragma unroll
    for (int i2 = 0; i2 < 2; i2++) {
        int gi = it * 32 + (ty << 1) + i2;
        #pragma unroll
        for (int j2 = 0; j2 < 2; j2++) {
            int gj = jt * 32 + (tx << 1) + j2;
            float mval = (!ap && mask[n * LSEQ + gj]) ? NEGINF : 0.0f;
            size_t idx = ((size_t)(n * 8 + h)) * LL2 + (size_t)gi * LSEQ + gj;
            S[idx] = acc[i2][j2] * 0.125f + biasb[idx] + mval;
        }
    }
}

// ---------------------------------------------------------------------------
// row softmax over 384 cols; one wave per row
__global__ __launch_bounds__(256) void softmax_kernel(float* __restrict__ S) {
    int lane = threadIdx.x & 63;
    int row  = blockIdx.x * 4 + (threadIdx.x >> 6);
    float* p = S + (size_t)row * LSEQ;
    float v[6];
    #pragma unroll
    for (int cc = 0; cc < 6; cc++) v[cc] = p[cc * 64 + lane];
    float mx = v[0];
    #pragma unroll
    for (int cc = 1; cc < 6; cc++) mx = fmaxf(mx, v[cc]);
    #pragma unroll
    for (int o = 32; o; o >>= 1) mx = fmaxf(mx, __shfl_xor(mx, o));
    float sum = 0.f;
    #pragma unroll
    for (int cc = 0; cc < 6; cc++) { v[cc] = expf(v[cc] - mx); sum += v[cc]; }
    #pragma unroll
    for (int o = 32; o; o >>= 1) sum += __shfl_xor(sum, o);
    float inv = 1.0f / sum;
    #pragma unroll
    for (int cc = 0; cc < 6; cc++) p[cc * 64 + lane] = v[cc] * inv;
}

// ---------------------------------------------------------------------------
// attn_out[n][i][h*64+d] = sum_j P[n,h,i,j] * v[n,j,h,d]   (zeroed if allpad)
// block = (it, h, n); 32 rows x 64 d; K-loop over j in steps of 64
__global__ __launch_bounds__(256) void av_kernel(const float* __restrict__ S,
                                                 const float* __restrict__ kv,
                                                 const int* __restrict__ allpad,
                                                 float* __restrict__ outb) {
    const int it = blockIdx.x, h = blockIdx.y, n = blockIdx.z;
    __shared__ float Ps[32][68];
    __shared__ float Vs[64][68];
    const int tid = threadIdx.x;
    const int tx = tid & 15, ty = tid >> 4;
    const int pr = tid >> 3, pc = (tid & 7) << 3;
    const int vr = tid >> 2, vc = (tid & 3) << 4;
    float acc0[4] = {0,0,0,0}, acc1[4] = {0,0,0,0};
    for (int j0 = 0; j0 < LSEQ; j0 += 64) {
        const float* sp = S + ((size_t)(n * 8 + h)) * LL2 + (size_t)(it * 32 + pr) * LSEQ + j0 + pc;
        float4 p0 = *(const float4*)sp;
        float4 p1 = *(const float4*)(sp + 4);
        *(float4*)&Ps[pr][pc]     = p0;
        *(float4*)&Ps[pr][pc + 4] = p1;
        #pragma unroll
        for (int u = 0; u < 4; u++) {
            float4 vvv = *(const float4*)&kv[((size_t)(n * LSEQ + j0 + vr)) * (2 * DMODEL)
                                             + DMODEL + h * HD2 + vc + 4 * u];
            *(float4*)&Vs[vr][vc + 4 * u] = vvv;
        }
        __syncthreads();
        #pragma unroll
        for (int j = 0; j < 64; j++) {
            float pa  = Ps[ty][j];
            float pb2 = Ps[ty + 16][j];
            float4 vv = *(const float4*)&Vs[j][tx << 2];
            acc0[0] = fmaf(pa,  vv.x, acc0[0]);
            acc0[1] = fmaf(pa,  vv.y, acc0[1]);
            acc0[2] = fmaf(pa,  vv.z, acc0[2]);
            acc0[3] = fmaf(pa,  vv.w, acc0[3]);
            acc1[0] = fmaf(pb2, vv.x, acc1[0]);
            acc1[1] = fmaf(pb2, vv.y, acc1[1]);
            acc1[2] = fmaf(pb2, vv.z, acc1[2]);
            acc1[3] = fmaf(pb2, vv.w, acc1[3]);
        }
        __syncthreads();
    }
    float zf = allpad[n] ? 0.0f : 1.0f;
    int i0 = it * 32;
    float4 o0 = {acc0[0]*zf, acc0[1]*zf, acc0[2]*zf, acc0[3]*zf};
    float4 o1 = {acc1[0]*zf, acc1[1]*zf, acc1[2]*zf, acc1[3]*zf};
    *(float4*)&outb[((size_t)(n * LSEQ + i0 + ty)) * DMODEL + h * HD2 + (tx << 2)]      = o0;
    *(float4*)&outb[((size_t)(n * LSEQ + i0 + ty + 16)) * DMODEL + h * HD2 + (tx << 2)] = o1;
}

// ---------------------------------------------------------------------------
extern "C" void kernel_launch(void* const* d_in, const int* in_sizes, int n_in,
                              void* d_out, int out_size, void* d_ws, size_t ws_size,
                              hipStream_t stream) {
    const float* x    = (const float*)d_in[0];
    const float* mem  = (const float*)d_in[1];
    const float* pd   = (const float*)d_in[2];
    const int*   mask = (const int*)d_in[3];
    const float* qw   = (const float*)d_in[4];
    const float* qbv  = (const float*)d_in[5];
    const float* kvw  = (const float*)d_in[6];
    const float* kvbv = (const float*)d_in[7];
    const float* pw   = (const float*)d_in[8];
    const float* pbv  = (const float*)d_in[9];
    const float* edw  = (const float*)d_in[10];
    const float* edb  = (const float*)d_in[11];
    const float* ln1g = (const float*)d_in[12];
    const float* ln1b = (const float*)d_in[13];
    const float* ln2g = (const float*)d_in[14];
    const float* ln2b = (const float*)d_in[15];
    const float* w1   = (const float*)d_in[16];
    const float* b1   = (const float*)d_in[17];
    const float* w2   = (const float*)d_in[18];
    const float* b2   = (const float*)d_in[19];
    const float* w3   = (const float*)d_in[20];
    const float* b3   = (const float*)d_in[21];

    float* wsf = (float*)d_ws;
    int*   allpad = (int*)d_ws;                   // 2 ints
    float* biasb  = wsf + 16;                     // N*H*L*L = 2359296
    float* scores = biasb + (size_t)NB * NH * LL2;       // 2359296
    float* a_in   = scores + (size_t)NB * NH * LL2;      // 393216
    float* a_mem  = a_in + ROWS * DMODEL;
    float* qbuf   = a_mem + ROWS * DMODEL;
    float* kvbuf  = qbuf + ROWS * DMODEL;                // 786432
    float* attnout= kvbuf + ROWS * 2 * DMODEL;
    float* x1buf  = attnout + ROWS * DMODEL;
    float* h0     = x1buf + ROWS * DMODEL;
    float* h1     = h0 + ROWS * DMODEL;                  // 1572864
    float* h2     = h1 + (size_t)ROWS * DMLP;            // 1572864

    float* outp = (float*)d_out;

    allpad_kernel<<<1, 128, 0, stream>>>(mask, allpad);
    ln_kernel<<<ROWS / 4, 256, 0, stream>>>(x, ln1g, ln1b, a_in);
    ln_kernel<<<ROWS / 4, 256, 0, stream>>>(mem, ln1g, ln1b, a_mem);
    bias_kernel<<<2048, 256, 0, stream>>>(pd, edw, edb, biasb);
    gemm_kernel<0, 0><<<dim3(8, 12), 256, 0, stream>>>(a_in, qw, qbv, nullptr, qbuf, ROWS, DMODEL, DMODEL);
    gemm_kernel<0, 0><<<dim3(16, 12), 256, 0, stream>>>(a_mem, kvw, kvbv, nullptr, kvbuf, ROWS, 2 * DMODEL, DMODEL);
    scores_kernel<<<dim3(144, NH, NB), 256, 0, stream>>>(qbuf, kvbuf, biasb, mask, allpad, scores);
    softmax_kernel<<<(NB * NH * LSEQ) / 4, 256, 0, stream>>>(scores);
    av_kernel<<<dim3(12, NH, NB), 256, 0, stream>>>(scores, kvbuf, allpad, attnout);
    gemm_kernel<0, 1><<<dim3(8, 12), 256, 0, stream>>>(attnout, pw, pbv, x, x1buf, ROWS, DMODEL, DMODEL);
    ln_kernel<<<ROWS / 4, 256, 0, stream>>>(x1buf, ln2g, ln2b, h0);
    gemm_kernel<1, 0><<<dim3(32, 12), 256, 0, stream>>>(h0, w1, b1, nullptr, h1, ROWS, DMLP, DMODEL);
    gemm_kernel<1, 0><<<dim3(32, 12), 256, 0, stream>>>(h1, w2, b2, nullptr, h2, ROWS, DMLP, DMLP);
    gemm_kernel<0, 1><<<dim3(8, 12), 256, 0, stream>>>(h2, w3, b3, x1buf, outp, ROWS, DMODEL, DMLP);
}

// Round 2
// 369.995 us; speedup vs baseline: 1.7521x; 1.7521x over previous
//
#include <hip/hip_runtime.h>
#include <hip/hip_bf16.h>
#include <math.h>

// Problem constants
#define NB   2
#define LSEQ 384
#define DMODEL 512
#define NH   8
#define HD2  64
#define DMLP 2048
#define LL2  (LSEQ*LSEQ)          // 147456
#define ROWS (NB*LSEQ)            // 768

using bf16x8 = __attribute__((ext_vector_type(8))) short;
using f32x4  = __attribute__((ext_vector_type(4))) float;

__device__ __forceinline__ unsigned short f2bf(float f) {
    union { __hip_bfloat16 h; unsigned short u; } cv;
    cv.h = __float2bfloat16(f);
    return cv.u;
}

__device__ __forceinline__ void gload_lds16(const void* g, void* l) {
    __builtin_amdgcn_global_load_lds(
        (const __attribute__((address_space(1))) void*)g,
        (__attribute__((address_space(3))) void*)l, 16, 0, 0);
}

// ---------------------------------------------------------------------------
// f32 -> bf16 elementwise convert (n divisible by 4)
__global__ __launch_bounds__(256) void cvt_kernel(const float* __restrict__ in,
                                                  unsigned short* __restrict__ out, int n) {
    int stride = gridDim.x * blockDim.x;
    for (int i = blockIdx.x * blockDim.x + threadIdx.x; i * 4 < n; i += stride) {
        float4 v = *(const float4*)(in + (size_t)i * 4);
        ushort4 o = {f2bf(v.x), f2bf(v.y), f2bf(v.z), f2bf(v.w)};
        *(ushort4*)(out + (size_t)i * 4) = o;
    }
}

// ---------------------------------------------------------------------------
// allpad[n] = all(mask[n, :])
__global__ void allpad_kernel(const int* __restrict__ mask, int* __restrict__ allpad) {
    int n = threadIdx.x >> 6, lane = threadIdx.x & 63;
    if (n < NB) {
        int pad = 1;
        for (int j = lane; j < LSEQ; j += 64) pad &= (mask[n * LSEQ + j] != 0) ? 1 : 0;
        unsigned long long bal = __ballot(pad != 0);
        if (lane == 0) allpad[n] = (bal == 0xFFFFFFFFFFFFFFFFull) ? 1 : 0;
    }
}

// ---------------------------------------------------------------------------
// LayerNorm: one wave per 512-elem row, 4 rows per block. OBF=1 -> bf16 out
template<int OBF>
__global__ __launch_bounds__(256) void ln_kernel(const float* __restrict__ src,
                                                 const float* __restrict__ g,
                                                 const float* __restrict__ b,
                                                 void* __restrict__ dstv) {
    int lane = threadIdx.x & 63;
    int row  = blockIdx.x * 4 + (threadIdx.x >> 6);
    const float* p = src + (size_t)row * DMODEL + lane * 8;
    float4 v0 = *(const float4*)p;
    float4 v1 = *(const float4*)(p + 4);
    float s  = v0.x + v0.y + v0.z + v0.w + v1.x + v1.y + v1.z + v1.w;
    float ss = v0.x*v0.x + v0.y*v0.y + v0.z*v0.z + v0.w*v0.w
             + v1.x*v1.x + v1.y*v1.y + v1.z*v1.z + v1.w*v1.w;
    #pragma unroll
    for (int o = 32; o; o >>= 1) { s += __shfl_xor(s, o); ss += __shfl_xor(ss, o); }
    float m   = s * (1.0f / DMODEL);
    float var = ss * (1.0f / DMODEL) - m * m;
    float r   = rsqrtf(var + 1e-5f);
    float4 g0 = *(const float4*)(g + lane * 8);
    float4 g1 = *(const float4*)(g + lane * 8 + 4);
    float4 b0 = *(const float4*)(b + lane * 8);
    float4 b1 = *(const float4*)(b + lane * 8 + 4);
    float o0[4], o1[4];
    o0[0] = (v0.x - m) * r * g0.x + b0.x;
    o0[1] = (v0.y - m) * r * g0.y + b0.y;
    o0[2] = (v0.z - m) * r * g0.z + b0.z;
    o0[3] = (v0.w - m) * r * g0.w + b0.w;
    o1[0] = (v1.x - m) * r * g1.x + b1.x;
    o1[1] = (v1.y - m) * r * g1.y + b1.y;
    o1[2] = (v1.z - m) * r * g1.z + b1.z;
    o1[3] = (v1.w - m) * r * g1.w + b1.w;
    if (OBF) {
        unsigned short* q = (unsigned short*)dstv + (size_t)row * DMODEL + lane * 8;
        ushort4 lo = {f2bf(o0[0]), f2bf(o0[1]), f2bf(o0[2]), f2bf(o0[3])};
        ushort4 hi = {f2bf(o1[0]), f2bf(o1[1]), f2bf(o1[2]), f2bf(o1[3])};
        *(ushort4*)q = lo;
        *(ushort4*)(q + 4) = hi;
    } else {
        float* q = (float*)dstv + (size_t)row * DMODEL + lane * 8;
        float4 lo = {o0[0], o0[1], o0[2], o0[3]};
        float4 hi = {o1[0], o1[1], o1[2], o1[3]};
        *(float4*)q = lo;
        *(float4*)(q + 4) = hi;
    }
}

// ---------------------------------------------------------------------------
// bias[n][h][i][j] = pd[n,i,j,:] . edw[h,:] + edb[h]
// one wave per (n,i,j) row of 512; edw held in registers (lane owns 8 elems)
__global__ __launch_bounds__(256) void bias_kernel(const float* __restrict__ pd,
                                                   const float* __restrict__ edw,
                                                   const float* __restrict__ edb,
                                                   float* __restrict__ biasb) {
    const int lane = threadIdx.x & 63;
    const int wid  = blockIdx.x * 4 + (threadIdx.x >> 6);
    const int nw   = gridDim.x * 4;
    float w[8][8];
    #pragma unroll
    for (int h = 0; h < 8; h++) {
        float4 aa = *(const float4*)&edw[h * DMODEL + lane * 8];
        float4 bb = *(const float4*)&edw[h * DMODEL + lane * 8 + 4];
        w[h][0]=aa.x; w[h][1]=aa.y; w[h][2]=aa.z; w[h][3]=aa.w;
        w[h][4]=bb.x; w[h][5]=bb.y; w[h][6]=bb.z; w[h][7]=bb.w;
    }
    float eb[8];
    #pragma unroll
    for (int h = 0; h < 8; h++) eb[h] = edb[h];

    const int total = NB * LL2; // 294912
    for (int row = wid; row < total; row += nw) {
        const float* src = pd + (size_t)row * DMODEL + lane * 8;
        float4 d0 = *(const float4*)src;
        float4 d1 = *(const float4*)(src + 4);
        float acc[8];
        #pragma unroll
        for (int h = 0; h < 8; h++) {
            acc[h] = d0.x*w[h][0] + d0.y*w[h][1] + d0.z*w[h][2] + d0.w*w[h][3]
                   + d1.x*w[h][4] + d1.y*w[h][5] + d1.z*w[h][6] + d1.w*w[h][7];
        }
        #pragma unroll
        for (int o = 32; o; o >>= 1) {
            #pragma unroll
            for (int h = 0; h < 8; h++) acc[h] += __shfl_xor(acc[h], o);
        }
        if (lane == 0) {
            int nidx = row / LL2;
            int ij   = row - nidx * LL2;
            size_t base = (size_t)nidx * 8 * LL2 + ij;
            #pragma unroll
            for (int h = 0; h < 8; h++) biasb[base + (size_t)h * LL2] = acc[h] + eb[h];
        }
    }
}

// ---------------------------------------------------------------------------
// bf16 MFMA GEMM: C[M,Nn] = op(A[M,K] @ W[Nn,K]^T + bv) (+ Rsd)
// A,W bf16 row-major; 64x64 tile, 256 threads (4 waves, each 32x32), BK=32
// global_load_lds width-16 staging; C/D layout: row=(lane>>4)*4+reg, col=lane&15
template<int ACT, int RES, int OBF>
__global__ __launch_bounds__(256) void mfma_gemm(const unsigned short* __restrict__ A,
                                                 const unsigned short* __restrict__ W,
                                                 const float* __restrict__ bv,
                                                 const float* __restrict__ Rsd,
                                                 void* __restrict__ Cv,
                                                 int M, int Nn, int K) {
    __shared__ short As[64 * 32];
    __shared__ short Ws[64 * 32];
    const int tid  = threadIdx.x;
    const int lane = tid & 63, wid = tid >> 6;
    const int wr = wid >> 1, wc = wid & 1;
    const int m0 = blockIdx.y * 64, n0 = blockIdx.x * 64;
    const int srow = tid >> 2, scol = (tid & 3) << 3;

    const unsigned short* ag = A + (size_t)(m0 + srow) * K + scol;
    const unsigned short* wg = W + (size_t)(n0 + srow) * K + scol;
    short* al = &As[tid * 8];
    short* wl = &Ws[tid * 8];

    f32x4 acc[2][2] = {};
    const int lr = lane >> 4, lc = lane & 15;

    for (int k0 = 0; k0 < K; k0 += 32) {
        gload_lds16(ag + k0, al);
        gload_lds16(wg + k0, wl);
        __syncthreads();   // compiler drains vmcnt before s_barrier
        bf16x8 af[2], bfr[2];
        #pragma unroll
        for (int m = 0; m < 2; m++)
            af[m] = *(const bf16x8*)&As[(wr * 32 + m * 16 + lc) * 32 + lr * 8];
        #pragma unroll
        for (int n = 0; n < 2; n++)
            bfr[n] = *(const bf16x8*)&Ws[(wc * 32 + n * 16 + lc) * 32 + lr * 8];
        #pragma unroll
        for (int m = 0; m < 2; m++)
            #pragma unroll
            for (int n = 0; n < 2; n++)
                acc[m][n] = __builtin_amdgcn_mfma_f32_16x16x32_bf16(af[m], bfr[n], acc[m][n], 0, 0, 0);
        __syncthreads();
    }

    #pragma unroll
    for (int n = 0; n < 2; n++) {
        int gcol = n0 + wc * 32 + n * 16 + lc;
        float bb = bv[gcol];
        #pragma unroll
        for (int m = 0; m < 2; m++) {
            #pragma unroll
            for (int r = 0; r < 4; r++) {
                int grow = m0 + wr * 32 + m * 16 + lr * 4 + r;
                float o = acc[m][n][r] + bb;
                if (ACT) o = o / (1.0f + expf(-o));
                if (RES) o += Rsd[(size_t)grow * Nn + gcol];
                if (OBF) ((unsigned short*)Cv)[(size_t)grow * Nn + gcol] = f2bf(o);
                else     ((float*)Cv)[(size_t)grow * Nn + gcol] = o;
            }
        }
    }
}

// ---------------------------------------------------------------------------
// scores[n,h,i,j] = 0.125 * q_i.k_j + bias[n,h,i,j] + mask
__global__ __launch_bounds__(256) void scores_kernel(const float* __restrict__ q,
                                                     const float* __restrict__ kv,
                                                     const float* __restrict__ biasb,
                                                     const int* __restrict__ mask,
                                                     const int* __restrict__ allpad,
                                                     float* __restrict__ S) {
    const int n = blockIdx.z, h = blockIdx.y;
    const int it = blockIdx.x / 12, jt = blockIdx.x % 12;
    __shared__ float Qs[64][32];
    __shared__ float Ks[64][32];
    const int tid = threadIdx.x;
    const int r = tid >> 3, c = (tid & 7) << 3;
    {
        const float* qp = q + ((size_t)(n * LSEQ + it * 32 + r)) * DMODEL + h * HD2 + c;
        float4 q0 = *(const float4*)qp;
        float4 q1 = *(const float4*)(qp + 4);
        Qs[c+0][r]=q0.x; Qs[c+1][r]=q0.y; Qs[c+2][r]=q0.z; Qs[c+3][r]=q0.w;
        Qs[c+4][r]=q1.x; Qs[c+5][r]=q1.y; Qs[c+6][r]=q1.z; Qs[c+7][r]=q1.w;
        const float* kp = kv + ((size_t)(n * LSEQ + jt * 32 + r)) * (2 * DMODEL) + h * HD2 + c;
        float4 k0 = *(const float4*)kp;
        float4 k1 = *(const float4*)(kp + 4);
        Ks[c+0][r]=k0.x; Ks[c+1][r]=k0.y; Ks[c+2][r]=k0.z; Ks[c+3][r]=k0.w;
        Ks[c+4][r]=k1.x; Ks[c+5][r]=k1.y; Ks[c+6][r]=k1.z; Ks[c+7][r]=k1.w;
    }
    __syncthreads();
    const int tx = tid & 15, ty = tid >> 4;
    float acc[2][2] = {{0.f,0.f},{0.f,0.f}};
    #pragma unroll
    for (int k = 0; k < 64; k++) {
        float2 a  = *(const float2*)&Qs[k][ty << 1];
        float2 b2 = *(const float2*)&Ks[k][tx << 1];
        acc[0][0] = fmaf(a.x, b2.x, acc[0][0]);
        acc[0][1] = fmaf(a.x, b2.y, acc[0][1]);
        acc[1][0] = fmaf(a.y, b2.x, acc[1][0]);
        acc[1][1] = fmaf(a.y, b2.y, acc[1][1]);
    }
    const int ap = allpad[n];
    const float NEGINF = -__builtin_inff();
    #pragma unroll
    for (int i2 = 0; i2 < 2; i2++) {
        int gi = it * 32 + (ty << 1) + i2;
        #pragma unroll
        for (int j2 = 0; j2 < 2; j2++) {
            int gj = jt * 32 + (tx << 1) + j2;
            float mval = (!ap && mask[n * LSEQ + gj]) ? NEGINF : 0.0f;
            size_t idx = ((size_t)(n * 8 + h)) * LL2 + (size_t)gi * LSEQ + gj;
            S[idx] = acc[i2][j2] * 0.125f + biasb[idx] + mval;
        }
    }
}

// ---------------------------------------------------------------------------
// row softmax over 384 cols; one wave per row
__global__ __launch_bounds__(256) void softmax_kernel(float* __restrict__ S) {
    int lane = threadIdx.x & 63;
    int row  = blockIdx.x * 4 + (threadIdx.x >> 6);
    float* p = S + (size_t)row * LSEQ;
    float v[6];
    #pragma unroll
    for (int cc = 0; cc < 6; cc++) v[cc] = p[cc * 64 + lane];
    float mx = v[0];
    #pragma unroll
    for (int cc = 1; cc < 6; cc++) mx = fmaxf(mx, v[cc]);
    #pragma unroll
    for (int o = 32; o; o >>= 1) mx = fmaxf(mx, __shfl_xor(mx, o));
    float sum = 0.f;
    #pragma unroll
    for (int cc = 0; cc < 6; cc++) { v[cc] = expf(v[cc] - mx); sum += v[cc]; }
    #pragma unroll
    for (int o = 32; o; o >>= 1) sum += __shfl_xor(sum, o);
    float inv = 1.0f / sum;
    #pragma unroll
    for (int cc = 0; cc < 6; cc++) p[cc * 64 + lane] = v[cc] * inv;
}

// ---------------------------------------------------------------------------
// attn_out[n][i][h*64+d] = sum_j P[n,h,i,j] * v[n,j,h,d]  -> bf16 out
__global__ __launch_bounds__(256) void av_kernel(const float* __restrict__ S,
                                                 const float* __restrict__ kv,
                                                 const int* __restrict__ allpad,
                                                 unsigned short* __restrict__ outb) {
    const int it = blockIdx.x, h = blockIdx.y, n = blockIdx.z;
    __shared__ float Ps[32][68];
    __shared__ float Vs[64][68];
    const int tid = threadIdx.x;
    const int tx = tid & 15, ty = tid >> 4;
    const int pr = tid >> 3, pc = (tid & 7) << 3;
    const int vr = tid >> 2, vc = (tid & 3) << 4;
    float acc0[4] = {0,0,0,0}, acc1[4] = {0,0,0,0};
    for (int j0 = 0; j0 < LSEQ; j0 += 64) {
        const float* sp = S + ((size_t)(n * 8 + h)) * LL2 + (size_t)(it * 32 + pr) * LSEQ + j0 + pc;
        float4 p0 = *(const float4*)sp;
        float4 p1 = *(const float4*)(sp + 4);
        *(float4*)&Ps[pr][pc]     = p0;
        *(float4*)&Ps[pr][pc + 4] = p1;
        #pragma unroll
        for (int u = 0; u < 4; u++) {
            float4 vvv = *(const float4*)&kv[((size_t)(n * LSEQ + j0 + vr)) * (2 * DMODEL)
                                             + DMODEL + h * HD2 + vc + 4 * u];
            *(float4*)&Vs[vr][vc + 4 * u] = vvv;
        }
        __syncthreads();
        #pragma unroll
        for (int j = 0; j < 64; j++) {
            float pa  = Ps[ty][j];
            float pb2 = Ps[ty + 16][j];
            float4 vv = *(const float4*)&Vs[j][tx << 2];
            acc0[0] = fmaf(pa,  vv.x, acc0[0]);
            acc0[1] = fmaf(pa,  vv.y, acc0[1]);
            acc0[2] = fmaf(pa,  vv.z, acc0[2]);
            acc0[3] = fmaf(pa,  vv.w, acc0[3]);
            acc1[0] = fmaf(pb2, vv.x, acc1[0]);
            acc1[1] = fmaf(pb2, vv.y, acc1[1]);
            acc1[2] = fmaf(pb2, vv.z, acc1[2]);
            acc1[3] = fmaf(pb2, vv.w, acc1[3]);
        }
        __syncthreads();
    }
    float zf = allpad[n] ? 0.0f : 1.0f;
    int i0 = it * 32;
    ushort4 o0 = {f2bf(acc0[0]*zf), f2bf(acc0[1]*zf), f2bf(acc0[2]*zf), f2bf(acc0[3]*zf)};
    ushort4 o1 = {f2bf(acc1[0]*zf), f2bf(acc1[1]*zf), f2bf(acc1[2]*zf), f2bf(acc1[3]*zf)};
    *(ushort4*)&outb[((size_t)(n * LSEQ + i0 + ty)) * DMODEL + h * HD2 + (tx << 2)]      = o0;
    *(ushort4*)&outb[((size_t)(n * LSEQ + i0 + ty + 16)) * DMODEL + h * HD2 + (tx << 2)] = o1;
}

// ---------------------------------------------------------------------------
extern "C" void kernel_launch(void* const* d_in, const int* in_sizes, int n_in,
                              void* d_out, int out_size, void* d_ws, size_t ws_size,
                              hipStream_t stream) {
    const float* x    = (const float*)d_in[0];
    const float* mem  = (const float*)d_in[1];
    const float* pd   = (const float*)d_in[2];
    const int*   mask = (const int*)d_in[3];
    const float* qw   = (const float*)d_in[4];
    const float* qbv  = (const float*)d_in[5];
    const float* kvw  = (const float*)d_in[6];
    const float* kvbv = (const float*)d_in[7];
    const float* pw   = (const float*)d_in[8];
    const float* pbv  = (const float*)d_in[9];
    const float* edw  = (const float*)d_in[10];
    const float* edb  = (const float*)d_in[11];
    const float* ln1g = (const float*)d_in[12];
    const float* ln1b = (const float*)d_in[13];
    const float* ln2g = (const float*)d_in[14];
    const float* ln2b = (const float*)d_in[15];
    const float* w1   = (const float*)d_in[16];
    const float* b1   = (const float*)d_in[17];
    const float* w2   = (const float*)d_in[18];
    const float* b2   = (const float*)d_in[19];
    const float* w3   = (const float*)d_in[20];
    const float* b3   = (const float*)d_in[21];

    float* wsf = (float*)d_ws;
    int*   allpad = (int*)d_ws;                          // 16 floats reserved
    float* biasb  = wsf + 16;                            // 2359296 f32
    float* scores = biasb + (size_t)NB * NH * LL2;       // 2359296 f32
    float* qbuf   = scores + (size_t)NB * NH * LL2;      // 393216 f32
    float* kvbuf  = qbuf + (size_t)ROWS * DMODEL;        // 786432 f32
    float* x1buf  = kvbuf + (size_t)ROWS * 2 * DMODEL;   // 393216 f32
    unsigned short* a_in  = (unsigned short*)(x1buf + (size_t)ROWS * DMODEL);
    unsigned short* a_mem = a_in  + (size_t)ROWS * DMODEL;
    unsigned short* attno = a_mem + (size_t)ROWS * DMODEL;
    unsigned short* h0    = attno + (size_t)ROWS * DMODEL;
    unsigned short* h1    = h0    + (size_t)ROWS * DMODEL;
    unsigned short* h2    = h1    + (size_t)ROWS * DMLP;
    unsigned short* qwb   = h2    + (size_t)ROWS * DMLP;
    unsigned short* kvwb  = qwb   + (size_t)DMODEL * DMODEL;
    unsigned short* pwb   = kvwb  + (size_t)2 * DMODEL * DMODEL;
    unsigned short* w1b   = pwb   + (size_t)DMODEL * DMODEL;
    unsigned short* w2b   = w1b   + (size_t)DMLP * DMODEL;
    unsigned short* w3b   = w2b   + (size_t)DMLP * DMLP;

    float* outp = (float*)d_out;

    // weight conversions f32 -> bf16
    cvt_kernel<<<256, 256, 0, stream>>>(qw,  qwb,  DMODEL * DMODEL);
    cvt_kernel<<<512, 256, 0, stream>>>(kvw, kvwb, 2 * DMODEL * DMODEL);
    cvt_kernel<<<256, 256, 0, stream>>>(pw,  pwb,  DMODEL * DMODEL);
    cvt_kernel<<<1024, 256, 0, stream>>>(w1, w1b, DMLP * DMODEL);
    cvt_kernel<<<2048, 256, 0, stream>>>(w2, w2b, DMLP * DMLP);
    cvt_kernel<<<1024, 256, 0, stream>>>(w3, w3b, DMLP * DMODEL);

    allpad_kernel<<<1, 128, 0, stream>>>(mask, allpad);
    ln_kernel<1><<<ROWS / 4, 256, 0, stream>>>(x,   ln1g, ln1b, a_in);
    ln_kernel<1><<<ROWS / 4, 256, 0, stream>>>(mem, ln1g, ln1b, a_mem);
    bias_kernel<<<2048, 256, 0, stream>>>(pd, edw, edb, biasb);

    mfma_gemm<0,0,0><<<dim3(DMODEL/64, ROWS/64), 256, 0, stream>>>(a_in,  qwb,  qbv,  nullptr, qbuf,  ROWS, DMODEL, DMODEL);
    mfma_gemm<0,0,0><<<dim3(2*DMODEL/64, ROWS/64), 256, 0, stream>>>(a_mem, kvwb, kvbv, nullptr, kvbuf, ROWS, 2*DMODEL, DMODEL);

    scores_kernel<<<dim3(144, NH, NB), 256, 0, stream>>>(qbuf, kvbuf, biasb, mask, allpad, scores);
    softmax_kernel<<<(NB * NH * LSEQ) / 4, 256, 0, stream>>>(scores);
    av_kernel<<<dim3(12, NH, NB), 256, 0, stream>>>(scores, kvbuf, allpad, attno);

    mfma_gemm<0,1,0><<<dim3(DMODEL/64, ROWS/64), 256, 0, stream>>>(attno, pwb, pbv, x, x1buf, ROWS, DMODEL, DMODEL);
    ln_kernel<1><<<ROWS / 4, 256, 0, stream>>>(x1buf, ln2g, ln2b, h0);
    mfma_gemm<1,0,1><<<dim3(DMLP/64, ROWS/64), 256, 0, stream>>>(h0, w1b, b1, nullptr, h1, ROWS, DMLP, DMODEL);
    mfma_gemm<1,0,1><<<dim3(DMLP/64, ROWS/64), 256, 0, stream>>>(h1, w2b, b2, nullptr, h2, ROWS, DMLP, DMLP);
    mfma_gemm<0,1,0><<<dim3(DMODEL/64, ROWS/64), 256, 0, stream>>>(h2, w3b, b3, x1buf, outp, ROWS, DMODEL, DMLP);
}

// Round 3
// 304.602 us; speedup vs baseline: 2.1282x; 1.2147x over previous
//
#include <hip/hip_runtime.h>
#include <hip/hip_bf16.h>
#include <math.h>

// Problem constants
#define NB   2
#define LSEQ 384
#define DMODEL 512
#define NH   8
#define HD2  64
#define DMLP 2048
#define LL2  (LSEQ*LSEQ)          // 147456
#define ROWS (NB*LSEQ)            // 768

using bf16x8 = __attribute__((ext_vector_type(8))) short;
using f32x4  = __attribute__((ext_vector_type(4))) float;

__device__ __forceinline__ unsigned short f2bf(float f) {
    union { __hip_bfloat16 h; unsigned short u; } cv;
    cv.h = __float2bfloat16(f);
    return cv.u;
}

__device__ __forceinline__ void gload_lds16(const void* g, void* l) {
    __builtin_amdgcn_global_load_lds(
        (const __attribute__((address_space(1))) void*)g,
        (__attribute__((address_space(3))) void*)l, 16, 0, 0);
}

// ---------------------------------------------------------------------------
// fused f32 -> bf16 conversion for all 6 weight matrices
__global__ __launch_bounds__(256) void cvt_all_kernel(
        const float* __restrict__ s0, const float* __restrict__ s1,
        const float* __restrict__ s2, const float* __restrict__ s3,
        const float* __restrict__ s4, const float* __restrict__ s5,
        unsigned short* __restrict__ d0, unsigned short* __restrict__ d1,
        unsigned short* __restrict__ d2, unsigned short* __restrict__ d3,
        unsigned short* __restrict__ d4, unsigned short* __restrict__ d5) {
    const int stride = gridDim.x * blockDim.x;
    const int t0 = blockIdx.x * blockDim.x + threadIdx.x;
    const float* srcs[6] = {s0, s1, s2, s3, s4, s5};
    unsigned short* dsts[6] = {d0, d1, d2, d3, d4, d5};
    const int nf4[6] = {DMODEL*DMODEL/4, 2*DMODEL*DMODEL/4, DMODEL*DMODEL/4,
                        DMLP*DMODEL/4, DMLP*DMLP/4, DMLP*DMODEL/4};
    #pragma unroll
    for (int a = 0; a < 6; a++) {
        const float* s = srcs[a];
        unsigned short* d = dsts[a];
        for (int i = t0; i < nf4[a]; i += stride) {
            float4 v = *(const float4*)(s + (size_t)i * 4);
            ushort4 o = {f2bf(v.x), f2bf(v.y), f2bf(v.z), f2bf(v.w)};
            *(ushort4*)(d + (size_t)i * 4) = o;
        }
    }
}

// ---------------------------------------------------------------------------
// LayerNorm: one wave per 512-elem row; rows < ROWS -> src0/dst0, else src1/dst1
__global__ __launch_bounds__(256) void ln_kernel(const float* __restrict__ src0,
                                                 const float* __restrict__ src1,
                                                 const float* __restrict__ g,
                                                 const float* __restrict__ b,
                                                 unsigned short* __restrict__ dst0,
                                                 unsigned short* __restrict__ dst1) {
    int lane = threadIdx.x & 63;
    int row  = blockIdx.x * 4 + (threadIdx.x >> 6);
    const float* src = (row < ROWS) ? src0 : src1;
    unsigned short* dst = (row < ROWS) ? dst0 : dst1;
    int r2 = (row < ROWS) ? row : row - ROWS;
    const float* p = src + (size_t)r2 * DMODEL + lane * 8;
    float4 v0 = *(const float4*)p;
    float4 v1 = *(const float4*)(p + 4);
    float s  = v0.x + v0.y + v0.z + v0.w + v1.x + v1.y + v1.z + v1.w;
    float ss = v0.x*v0.x + v0.y*v0.y + v0.z*v0.z + v0.w*v0.w
             + v1.x*v1.x + v1.y*v1.y + v1.z*v1.z + v1.w*v1.w;
    #pragma unroll
    for (int o = 32; o; o >>= 1) { s += __shfl_xor(s, o); ss += __shfl_xor(ss, o); }
    float m   = s * (1.0f / DMODEL);
    float var = ss * (1.0f / DMODEL) - m * m;
    float r   = rsqrtf(var + 1e-5f);
    float4 g0 = *(const float4*)(g + lane * 8);
    float4 g1 = *(const float4*)(g + lane * 8 + 4);
    float4 b0 = *(const float4*)(b + lane * 8);
    float4 b1 = *(const float4*)(b + lane * 8 + 4);
    unsigned short* q = dst + (size_t)r2 * DMODEL + lane * 8;
    ushort4 lo = {f2bf((v0.x - m) * r * g0.x + b0.x), f2bf((v0.y - m) * r * g0.y + b0.y),
                  f2bf((v0.z - m) * r * g0.z + b0.z), f2bf((v0.w - m) * r * g0.w + b0.w)};
    ushort4 hi = {f2bf((v1.x - m) * r * g1.x + b1.x), f2bf((v1.y - m) * r * g1.y + b1.y),
                  f2bf((v1.z - m) * r * g1.z + b1.z), f2bf((v1.w - m) * r * g1.w + b1.w)};
    *(ushort4*)q = lo;
    *(ushort4*)(q + 4) = hi;
}

// ---------------------------------------------------------------------------
// bias[n][h][ij] = pd[row=n*LL2+ij, :512] . edw[h,:] + edb[h] + mask(-inf)
// MFMA version: per wave, 16 rows x 16 cols (8 heads valid), K=512 in 16 steps.
// A loaded f32 from global -> cvt to bf16 in-reg; B (edw) staged bf16 in LDS.
#define BTILES (NB * LL2 / 16)   // 18432
__global__ __launch_bounds__(256) void bias_mfma(const float* __restrict__ pd,
                                                 const float* __restrict__ edw,
                                                 const float* __restrict__ edb,
                                                 const int* __restrict__ mask,
                                                 float* __restrict__ biasb) {
    __shared__ short ew[16 * 528];   // 16 cols x 512 k, stride 528 (16B aligned)
    const int tid = threadIdx.x;
    for (int idx = tid; idx < 16 * 512; idx += 256) {
        int col = idx >> 9, k = idx & 511;
        float v = (col < 8) ? edw[col * 512 + k] : 0.0f;
        ew[col * 528 + k] = (short)f2bf(v);
    }
    const int lane = tid & 63, w = tid >> 6;
    // allpad per n, computed in-wave
    int ap[NB];
    #pragma unroll
    for (int n = 0; n < NB; n++) {
        int pad = 1;
        for (int j = lane; j < LSEQ; j += 64) pad &= (mask[n * LSEQ + j] != 0) ? 1 : 0;
        unsigned long long bal = __ballot(pad != 0);
        ap[n] = (bal == 0xFFFFFFFFFFFFFFFFull) ? 1 : 0;
    }
    __syncthreads();

    const int c = lane & 15, g = lane >> 4;
    const float eb = (c < 8) ? edb[c] : 0.0f;
    const int gw = blockIdx.x * 4 + w;       // 1536*4 = 6144 waves
    const float NEGINF = -__builtin_inff();

    for (int t = gw; t < BTILES; t += 6144) {
        const int m0 = t * 16;
        const float* arow = pd + (size_t)(m0 + c) * DMODEL + g * 8;
        f32x4 acc = {};
        #pragma unroll
        for (int ks = 0; ks < 16; ks++) {
            float4 a0 = *(const float4*)(arow + ks * 32);
            float4 a1 = *(const float4*)(arow + ks * 32 + 4);
            bf16x8 af;
            af[0] = (short)f2bf(a0.x); af[1] = (short)f2bf(a0.y);
            af[2] = (short)f2bf(a0.z); af[3] = (short)f2bf(a0.w);
            af[4] = (short)f2bf(a1.x); af[5] = (short)f2bf(a1.y);
            af[6] = (short)f2bf(a1.z); af[7] = (short)f2bf(a1.w);
            bf16x8 bfv = *(const bf16x8*)&ew[c * 528 + ks * 32 + g * 8];
            acc = __builtin_amdgcn_mfma_f32_16x16x32_bf16(af, bfv, acc, 0, 0, 0);
        }
        if (c < 8) {
            const int n   = m0 / LL2;              // tile never crosses n
            const int ij0 = (m0 - n * LL2) + g * 4;
            const int j0  = ij0 % LSEQ;            // 4 consecutive j, same i
            int4 mv = *(const int4*)&mask[n * LSEQ + j0];
            float4 o;
            o.x = acc[0] + eb + ((!ap[n] && mv.x) ? NEGINF : 0.0f);
            o.y = acc[1] + eb + ((!ap[n] && mv.y) ? NEGINF : 0.0f);
            o.z = acc[2] + eb + ((!ap[n] && mv.z) ? NEGINF : 0.0f);
            o.w = acc[3] + eb + ((!ap[n] && mv.w) ? NEGINF : 0.0f);
            *(float4*)&biasb[((size_t)(n * 8 + c)) * LL2 + ij0] = o;
        }
    }
}

// ---------------------------------------------------------------------------
// bf16 MFMA GEMM: C[M,Nn] = op(A[M,K] @ W[Nn,K]^T + bv) (+ Rsd)
// 64x64 tile, 4 waves (2x2 of 32x32), BK=64, XOR-swizzled LDS (pre-swizzled
// global source + swizzled ds_read; rule #21).
template<int ACT, int RES, int OBF>
__global__ __launch_bounds__(256) void mfma_gemm(const unsigned short* __restrict__ A,
                                                 const unsigned short* __restrict__ W,
                                                 const float* __restrict__ bv,
                                                 const float* __restrict__ Rsd,
                                                 void* __restrict__ Cv,
                                                 int M, int Nn, int K) {
    __shared__ short As[64 * 64];
    __shared__ short Ws[64 * 64];
    const int tid  = threadIdx.x;
    const int lane = tid & 63, w = tid >> 6;
    const int wr = w >> 1, wc = w & 1;
    const int m0 = blockIdx.y * 64, n0 = blockIdx.x * 64;
    // staging: slot s = q*256+tid holds 8 bf16; row=s>>3, stored chunk cs=s&7,
    // source colchunk = cs ^ (row&7)
    const int s0 = tid, s1 = 256 + tid;
    const int r0 = s0 >> 3, c0 = ((s0 & 7) ^ (r0 & 7)) << 3;
    const int r1 = s1 >> 3, c1 = ((s1 & 7) ^ (r1 & 7)) << 3;
    const unsigned short* ag0 = A + (size_t)(m0 + r0) * K + c0;
    const unsigned short* ag1 = A + (size_t)(m0 + r1) * K + c1;
    const unsigned short* wg0 = W + (size_t)(n0 + r0) * K + c0;
    const unsigned short* wg1 = W + (size_t)(n0 + r1) * K + c1;

    f32x4 acc[2][2] = {};
    const int lc = lane & 15, lr = lane >> 4;

    for (int k0 = 0; k0 < K; k0 += 64) {
        gload_lds16(ag0 + k0, &As[s0 * 8]);
        gload_lds16(ag1 + k0, &As[s1 * 8]);
        gload_lds16(wg0 + k0, &Ws[s0 * 8]);
        gload_lds16(wg1 + k0, &Ws[s1 * 8]);
        __syncthreads();
        bf16x8 af[2][2], bf[2][2];
        #pragma unroll
        for (int m = 0; m < 2; m++) {
            int rr = wr * 32 + m * 16 + lc;
            #pragma unroll
            for (int kk = 0; kk < 2; kk++) {
                int cc = (lr + kk * 4) ^ (rr & 7);
                af[m][kk] = *(const bf16x8*)&As[rr * 64 + cc * 8];
            }
        }
        #pragma unroll
        for (int n = 0; n < 2; n++) {
            int rr = wc * 32 + n * 16 + lc;
            #pragma unroll
            for (int kk = 0; kk < 2; kk++) {
                int cc = (lr + kk * 4) ^ (rr & 7);
                bf[n][kk] = *(const bf16x8*)&Ws[rr * 64 + cc * 8];
            }
        }
        #pragma unroll
        for (int m = 0; m < 2; m++)
            #pragma unroll
            for (int n = 0; n < 2; n++) {
                acc[m][n] = __builtin_amdgcn_mfma_f32_16x16x32_bf16(af[m][0], bf[n][0], acc[m][n], 0, 0, 0);
                acc[m][n] = __builtin_amdgcn_mfma_f32_16x16x32_bf16(af[m][1], bf[n][1], acc[m][n], 0, 0, 0);
            }
        __syncthreads();
    }

    #pragma unroll
    for (int n = 0; n < 2; n++) {
        int gcol = n0 + wc * 32 + n * 16 + lc;
        float bb = bv[gcol];
        #pragma unroll
        for (int m = 0; m < 2; m++) {
            #pragma unroll
            for (int r = 0; r < 4; r++) {
                int grow = m0 + wr * 32 + m * 16 + lr * 4 + r;
                float o = acc[m][n][r] + bb;
                if (ACT) o = o / (1.0f + expf(-o));
                if (RES) o += Rsd[(size_t)grow * Nn + gcol];
                if (OBF) ((unsigned short*)Cv)[(size_t)grow * Nn + gcol] = f2bf(o);
                else     ((float*)Cv)[(size_t)grow * Nn + gcol] = o;
            }
        }
    }
}

// ---------------------------------------------------------------------------
// scores[n,h,i,j] = 0.125 * q_i.k_j + biasb[n,h,i,j]   (mask pre-folded)
__global__ __launch_bounds__(256) void scores_kernel(const float* __restrict__ q,
                                                     const float* __restrict__ kv,
                                                     const float* __restrict__ biasb,
                                                     float* __restrict__ S) {
    const int n = blockIdx.z, h = blockIdx.y;
    const int it = blockIdx.x / 12, jt = blockIdx.x % 12;
    __shared__ float Qs[64][32];
    __shared__ float Ks[64][32];
    const int tid = threadIdx.x;
    const int r = tid >> 3, c = (tid & 7) << 3;
    {
        const float* qp = q + ((size_t)(n * LSEQ + it * 32 + r)) * DMODEL + h * HD2 + c;
        float4 q0 = *(const float4*)qp;
        float4 q1 = *(const float4*)(qp + 4);
        Qs[c+0][r]=q0.x; Qs[c+1][r]=q0.y; Qs[c+2][r]=q0.z; Qs[c+3][r]=q0.w;
        Qs[c+4][r]=q1.x; Qs[c+5][r]=q1.y; Qs[c+6][r]=q1.z; Qs[c+7][r]=q1.w;
        const float* kp = kv + ((size_t)(n * LSEQ + jt * 32 + r)) * (2 * DMODEL) + h * HD2 + c;
        float4 k0 = *(const float4*)kp;
        float4 k1 = *(const float4*)(kp + 4);
        Ks[c+0][r]=k0.x; Ks[c+1][r]=k0.y; Ks[c+2][r]=k0.z; Ks[c+3][r]=k0.w;
        Ks[c+4][r]=k1.x; Ks[c+5][r]=k1.y; Ks[c+6][r]=k1.z; Ks[c+7][r]=k1.w;
    }
    __syncthreads();
    const int tx = tid & 15, ty = tid >> 4;
    float acc[2][2] = {{0.f,0.f},{0.f,0.f}};
    #pragma unroll
    for (int k = 0; k < 64; k++) {
        float2 a  = *(const float2*)&Qs[k][ty << 1];
        float2 b2 = *(const float2*)&Ks[k][tx << 1];
        acc[0][0] = fmaf(a.x, b2.x, acc[0][0]);
        acc[0][1] = fmaf(a.x, b2.y, acc[0][1]);
        acc[1][0] = fmaf(a.y, b2.x, acc[1][0]);
        acc[1][1] = fmaf(a.y, b2.y, acc[1][1]);
    }
    #pragma unroll
    for (int i2 = 0; i2 < 2; i2++) {
        int gi = it * 32 + (ty << 1) + i2;
        #pragma unroll
        for (int j2 = 0; j2 < 2; j2++) {
            int gj = jt * 32 + (tx << 1) + j2;
            size_t idx = ((size_t)(n * 8 + h)) * LL2 + (size_t)gi * LSEQ + gj;
            S[idx] = acc[i2][j2] * 0.125f + biasb[idx];
        }
    }
}

// ---------------------------------------------------------------------------
// row softmax over 384 cols; one wave per row
__global__ __launch_bounds__(256) void softmax_kernel(float* __restrict__ S) {
    int lane = threadIdx.x & 63;
    int row  = blockIdx.x * 4 + (threadIdx.x >> 6);
    float* p = S + (size_t)row * LSEQ;
    float v[6];
    #pragma unroll
    for (int cc = 0; cc < 6; cc++) v[cc] = p[cc * 64 + lane];
    float mx = v[0];
    #pragma unroll
    for (int cc = 1; cc < 6; cc++) mx = fmaxf(mx, v[cc]);
    #pragma unroll
    for (int o = 32; o; o >>= 1) mx = fmaxf(mx, __shfl_xor(mx, o));
    float sum = 0.f;
    #pragma unroll
    for (int cc = 0; cc < 6; cc++) { v[cc] = expf(v[cc] - mx); sum += v[cc]; }
    #pragma unroll
    for (int o = 32; o; o >>= 1) sum += __shfl_xor(sum, o);
    float inv = 1.0f / sum;
    #pragma unroll
    for (int cc = 0; cc < 6; cc++) p[cc * 64 + lane] = v[cc] * inv;
}

// ---------------------------------------------------------------------------
// attn_out = P @ V  -> bf16; allpad computed in-wave
__global__ __launch_bounds__(256) void av_kernel(const float* __restrict__ S,
                                                 const float* __restrict__ kv,
                                                 const int* __restrict__ mask,
                                                 unsigned short* __restrict__ outb) {
    const int it = blockIdx.x, h = blockIdx.y, n = blockIdx.z;
    __shared__ float Ps[32][68];
    __shared__ float Vs[64][68];
    const int tid = threadIdx.x;
    const int lane = tid & 63;
    int pad = 1;
    for (int j = lane; j < LSEQ; j += 64) pad &= (mask[n * LSEQ + j] != 0) ? 1 : 0;
    unsigned long long bal = __ballot(pad != 0);
    const float zf = (bal == 0xFFFFFFFFFFFFFFFFull) ? 0.0f : 1.0f;
    const int tx = tid & 15, ty = tid >> 4;
    const int pr = tid >> 3, pc = (tid & 7) << 3;
    const int vr = tid >> 2, vc = (tid & 3) << 4;
    float acc0[4] = {0,0,0,0}, acc1[4] = {0,0,0,0};
    for (int j0 = 0; j0 < LSEQ; j0 += 64) {
        const float* sp = S + ((size_t)(n * 8 + h)) * LL2 + (size_t)(it * 32 + pr) * LSEQ + j0 + pc;
        float4 p0 = *(const float4*)sp;
        float4 p1 = *(const float4*)(sp + 4);
        *(float4*)&Ps[pr][pc]     = p0;
        *(float4*)&Ps[pr][pc + 4] = p1;
        #pragma unroll
        for (int u = 0; u < 4; u++) {
            float4 vvv = *(const float4*)&kv[((size_t)(n * LSEQ + j0 + vr)) * (2 * DMODEL)
                                             + DMODEL + h * HD2 + vc + 4 * u];
            *(float4*)&Vs[vr][vc + 4 * u] = vvv;
        }
        __syncthreads();
        #pragma unroll
        for (int j = 0; j < 64; j++) {
            float pa  = Ps[ty][j];
            float pb2 = Ps[ty + 16][j];
            float4 vv = *(const float4*)&Vs[j][tx << 2];
            acc0[0] = fmaf(pa,  vv.x, acc0[0]);
            acc0[1] = fmaf(pa,  vv.y, acc0[1]);
            acc0[2] = fmaf(pa,  vv.z, acc0[2]);
            acc0[3] = fmaf(pa,  vv.w, acc0[3]);
            acc1[0] = fmaf(pb2, vv.x, acc1[0]);
            acc1[1] = fmaf(pb2, vv.y, acc1[1]);
            acc1[2] = fmaf(pb2, vv.z, acc1[2]);
            acc1[3] = fmaf(pb2, vv.w, acc1[3]);
        }
        __syncthreads();
    }
    int i0 = it * 32;
    ushort4 o0 = {f2bf(acc0[0]*zf), f2bf(acc0[1]*zf), f2bf(acc0[2]*zf), f2bf(acc0[3]*zf)};
    ushort4 o1 = {f2bf(acc1[0]*zf), f2bf(acc1[1]*zf), f2bf(acc1[2]*zf), f2bf(acc1[3]*zf)};
    *(ushort4*)&outb[((size_t)(n * LSEQ + i0 + ty)) * DMODEL + h * HD2 + (tx << 2)]      = o0;
    *(ushort4*)&outb[((size_t)(n * LSEQ + i0 + ty + 16)) * DMODEL + h * HD2 + (tx << 2)] = o1;
}

// ---------------------------------------------------------------------------
extern "C" void kernel_launch(void* const* d_in, const int* in_sizes, int n_in,
                              void* d_out, int out_size, void* d_ws, size_t ws_size,
                              hipStream_t stream) {
    const float* x    = (const float*)d_in[0];
    const float* mem  = (const float*)d_in[1];
    const float* pd   = (const float*)d_in[2];
    const int*   mask = (const int*)d_in[3];
    const float* qw   = (const float*)d_in[4];
    const float* qbv  = (const float*)d_in[5];
    const float* kvw  = (const float*)d_in[6];
    const float* kvbv = (const float*)d_in[7];
    const float* pw   = (const float*)d_in[8];
    const float* pbv  = (const float*)d_in[9];
    const float* edw  = (const float*)d_in[10];
    const float* edb  = (const float*)d_in[11];
    const float* ln1g = (const float*)d_in[12];
    const float* ln1b = (const float*)d_in[13];
    const float* ln2g = (const float*)d_in[14];
    const float* ln2b = (const float*)d_in[15];
    const float* w1   = (const float*)d_in[16];
    const float* b1   = (const float*)d_in[17];
    const float* w2   = (const float*)d_in[18];
    const float* b2   = (const float*)d_in[19];
    const float* w3   = (const float*)d_in[20];
    const float* b3   = (const float*)d_in[21];

    float* wsf = (float*)d_ws;
    float* biasb  = wsf + 16;                            // 2359296 f32
    float* scores = biasb + (size_t)NB * NH * LL2;       // 2359296 f32
    float* qbuf   = scores + (size_t)NB * NH * LL2;      // 393216 f32
    float* kvbuf  = qbuf + (size_t)ROWS * DMODEL;        // 786432 f32
    float* x1buf  = kvbuf + (size_t)ROWS * 2 * DMODEL;   // 393216 f32
    unsigned short* a_in  = (unsigned short*)(x1buf + (size_t)ROWS * DMODEL);
    unsigned short* a_mem = a_in  + (size_t)ROWS * DMODEL;
    unsigned short* attno = a_mem + (size_t)ROWS * DMODEL;
    unsigned short* h0    = attno + (size_t)ROWS * DMODEL;
    unsigned short* h1    = h0    + (size_t)ROWS * DMODEL;
    unsigned short* h2    = h1    + (size_t)ROWS * DMLP;
    unsigned short* qwb   = h2    + (size_t)ROWS * DMLP;
    unsigned short* kvwb  = qwb   + (size_t)DMODEL * DMODEL;
    unsigned short* pwb   = kvwb  + (size_t)2 * DMODEL * DMODEL;
    unsigned short* w1b   = pwb   + (size_t)DMODEL * DMODEL;
    unsigned short* w2b   = w1b   + (size_t)DMLP * DMODEL;
    unsigned short* w3b   = w2b   + (size_t)DMLP * DMLP;

    float* outp = (float*)d_out;

    cvt_all_kernel<<<2048, 256, 0, stream>>>(qw, kvw, pw, w1, w2, w3,
                                             qwb, kvwb, pwb, w1b, w2b, w3b);
    ln_kernel<<<2 * ROWS / 4, 256, 0, stream>>>(x, mem, ln1g, ln1b, a_in, a_mem);
    bias_mfma<<<1536, 256, 0, stream>>>(pd, edw, edb, mask, biasb);

    mfma_gemm<0,0,0><<<dim3(DMODEL/64, ROWS/64), 256, 0, stream>>>(a_in,  qwb,  qbv,  nullptr, qbuf,  ROWS, DMODEL, DMODEL);
    mfma_gemm<0,0,0><<<dim3(2*DMODEL/64, ROWS/64), 256, 0, stream>>>(a_mem, kvwb, kvbv, nullptr, kvbuf, ROWS, 2*DMODEL, DMODEL);

    scores_kernel<<<dim3(144, NH, NB), 256, 0, stream>>>(qbuf, kvbuf, biasb, scores);
    softmax_kernel<<<(NB * NH * LSEQ) / 4, 256, 0, stream>>>(scores);
    av_kernel<<<dim3(12, NH, NB), 256, 0, stream>>>(scores, kvbuf, mask, attno);

    mfma_gemm<0,1,0><<<dim3(DMODEL/64, ROWS/64), 256, 0, stream>>>(attno, pwb, pbv, x, x1buf, ROWS, DMODEL, DMODEL);
    ln_kernel<<<ROWS / 4, 256, 0, stream>>>(x1buf, x1buf, ln2g, ln2b, h0, h0);
    mfma_gemm<1,0,1><<<dim3(DMLP/64, ROWS/64), 256, 0, stream>>>(h0, w1b, b1, nullptr, h1, ROWS, DMLP, DMODEL);
    mfma_gemm<1,0,1><<<dim3(DMLP/64, ROWS/64), 256, 0, stream>>>(h1, w2b, b2, nullptr, h2, ROWS, DMLP, DMLP);
    mfma_gemm<0,1,0><<<dim3(DMODEL/64, ROWS/64), 256, 0, stream>>>(h2, w3b, b3, x1buf, outp, ROWS, DMODEL, DMLP);
}

// Round 4
// 264.224 us; speedup vs baseline: 2.4534x; 1.1528x over previous
//
#include <hip/hip_runtime.h>
#include <hip/hip_bf16.h>
#include <math.h>

// Problem constants
#define NB   2
#define LSEQ 384
#define DMODEL 512
#define NH   8
#define HD2  64
#define DMLP 2048
#define LL2  (LSEQ*LSEQ)          // 147456
#define ROWS (NB*LSEQ)            // 768

using bf16x8 = __attribute__((ext_vector_type(8))) short;
using f32x4  = __attribute__((ext_vector_type(4))) float;

__device__ __forceinline__ unsigned short f2bf(float f) {
    union { __hip_bfloat16 h; unsigned short u; } cv;
    cv.h = __float2bfloat16(f);
    return cv.u;
}

__device__ __forceinline__ void gload_lds16(const void* g, void* l) {
    __builtin_amdgcn_global_load_lds(
        (const __attribute__((address_space(1))) void*)g,
        (__attribute__((address_space(3))) void*)l, 16, 0, 0);
}

__device__ __forceinline__ void wait_vmcnt(int rem) {
    if (rem >= 3)      asm volatile("s_waitcnt vmcnt(12)" ::: "memory");
    else if (rem == 2) asm volatile("s_waitcnt vmcnt(8)"  ::: "memory");
    else if (rem == 1) asm volatile("s_waitcnt vmcnt(4)"  ::: "memory");
    else               asm volatile("s_waitcnt vmcnt(0)"  ::: "memory");
}

// ---------------------------------------------------------------------------
// fused f32 -> bf16 conversion: 6 weight matrices + padded edw table (16x512)
__global__ __launch_bounds__(256) void cvt_all_kernel(
        const float* __restrict__ s0, const float* __restrict__ s1,
        const float* __restrict__ s2, const float* __restrict__ s3,
        const float* __restrict__ s4, const float* __restrict__ s5,
        const float* __restrict__ edw,
        unsigned short* __restrict__ d0, unsigned short* __restrict__ d1,
        unsigned short* __restrict__ d2, unsigned short* __restrict__ d3,
        unsigned short* __restrict__ d4, unsigned short* __restrict__ d5,
        unsigned short* __restrict__ edwb) {
    const int stride = gridDim.x * blockDim.x;
    const int t0 = blockIdx.x * blockDim.x + threadIdx.x;
    const float* srcs[6] = {s0, s1, s2, s3, s4, s5};
    unsigned short* dsts[6] = {d0, d1, d2, d3, d4, d5};
    const int nf4[6] = {DMODEL*DMODEL/4, 2*DMODEL*DMODEL/4, DMODEL*DMODEL/4,
                        DMLP*DMODEL/4, DMLP*DMLP/4, DMLP*DMODEL/4};
    #pragma unroll
    for (int a = 0; a < 6; a++) {
        const float* s = srcs[a];
        unsigned short* d = dsts[a];
        for (int i = t0; i < nf4[a]; i += stride) {
            float4 v = *(const float4*)(s + (size_t)i * 4);
            ushort4 o = {f2bf(v.x), f2bf(v.y), f2bf(v.z), f2bf(v.w)};
            *(ushort4*)(d + (size_t)i * 4) = o;
        }
    }
    // edw padded to 16 rows (rows 8..15 zero)
    for (int i = t0; i < 16 * 512 / 4; i += stride) {
        int row = (i * 4) >> 9;
        float4 v = {0.f, 0.f, 0.f, 0.f};
        if (row < 8) v = *(const float4*)(edw + (size_t)i * 4);
        ushort4 o = {f2bf(v.x), f2bf(v.y), f2bf(v.z), f2bf(v.w)};
        *(ushort4*)(edwb + (size_t)i * 4) = o;
    }
}

// ---------------------------------------------------------------------------
// LayerNorm: one wave per 512-elem row; rows < ROWS -> src0/dst0, else src1/dst1
__global__ __launch_bounds__(256) void ln_kernel(const float* __restrict__ src0,
                                                 const float* __restrict__ src1,
                                                 const float* __restrict__ g,
                                                 const float* __restrict__ b,
                                                 unsigned short* __restrict__ dst0,
                                                 unsigned short* __restrict__ dst1) {
    int lane = threadIdx.x & 63;
    int row  = blockIdx.x * 4 + (threadIdx.x >> 6);
    const float* src = (row < ROWS) ? src0 : src1;
    unsigned short* dst = (row < ROWS) ? dst0 : dst1;
    int r2 = (row < ROWS) ? row : row - ROWS;
    const float* p = src + (size_t)r2 * DMODEL + lane * 8;
    float4 v0 = *(const float4*)p;
    float4 v1 = *(const float4*)(p + 4);
    float s  = v0.x + v0.y + v0.z + v0.w + v1.x + v1.y + v1.z + v1.w;
    float ss = v0.x*v0.x + v0.y*v0.y + v0.z*v0.z + v0.w*v0.w
             + v1.x*v1.x + v1.y*v1.y + v1.z*v1.z + v1.w*v1.w;
    #pragma unroll
    for (int o = 32; o; o >>= 1) { s += __shfl_xor(s, o); ss += __shfl_xor(ss, o); }
    float m   = s * (1.0f / DMODEL);
    float var = ss * (1.0f / DMODEL) - m * m;
    float r   = rsqrtf(var + 1e-5f);
    float4 g0 = *(const float4*)(g + lane * 8);
    float4 g1 = *(const float4*)(g + lane * 8 + 4);
    float4 b0 = *(const float4*)(b + lane * 8);
    float4 b1 = *(const float4*)(b + lane * 8 + 4);
    unsigned short* q = dst + (size_t)r2 * DMODEL + lane * 8;
    ushort4 lo = {f2bf((v0.x - m) * r * g0.x + b0.x), f2bf((v0.y - m) * r * g0.y + b0.y),
                  f2bf((v0.z - m) * r * g0.z + b0.z), f2bf((v0.w - m) * r * g0.w + b0.w)};
    ushort4 hi = {f2bf((v1.x - m) * r * g1.x + b1.x), f2bf((v1.y - m) * r * g1.y + b1.y),
                  f2bf((v1.z - m) * r * g1.z + b1.z), f2bf((v1.w - m) * r * g1.w + b1.w)};
    *(ushort4*)q = lo;
    *(ushort4*)(q + 4) = hi;
}

// ---------------------------------------------------------------------------
// bias v2: coalesced gload_lds staging of pd (f32, XOR-swizzled source),
// 2-phase double buffer. Block = 64 ij-rows (same n,i), waves own 16 rows.
// B-operand: edwb (bf16, 16x512, zero-padded) read from global (L1-hot).
__global__ __launch_bounds__(256) void bias_mfma(const float* __restrict__ pd,
                                                 const unsigned short* __restrict__ edwb,
                                                 const float* __restrict__ edb,
                                                 const int* __restrict__ mask,
                                                 float* __restrict__ biasb) {
    __shared__ float Asb[2][64 * 64];    // 2 x 16KB: 64 rows x 64 f32 (one k-chunk)
    const int tid = threadIdx.x;
    const int lane = tid & 63, w = tid >> 6;
    const int T = blockIdx.x;            // 4608 tiles of 64 ij
    const size_t row0 = (size_t)T * 64;
    const int n = T / 2304;
    const int rem64 = (T - n * 2304) * 64;
    const int i = rem64 / LSEQ, j0 = rem64 % LSEQ;

    // allpad for this n (in-wave)
    int pad = 1;
    for (int j = lane; j < LSEQ; j += 64) pad &= (mask[n * LSEQ + j] != 0) ? 1 : 0;
    unsigned long long bal = __ballot(pad);
    const int ap = (bal == ~0ull) ? 1 : 0;

    // staging map: slot s = q*256+tid -> row r = s>>4, stored chunk cs = s&15,
    // source chunk = (cs&8) | ((cs&7) ^ (r&7))   (16B chunks, 16 per row)
    int rr[4], sc[4];
    #pragma unroll
    for (int q = 0; q < 4; q++) {
        int s = q * 256 + tid;
        rr[q] = s >> 4;
        int cs = s & 15;
        sc[q] = (cs & 8) | ((cs & 7) ^ (rr[q] & 7));
    }

    const int c = lane & 15, g = lane >> 4;
    f32x4 acc = {};

    // prologue: stage kc=0 into buf 0
    #pragma unroll
    for (int q = 0; q < 4; q++)
        gload_lds16(pd + (row0 + rr[q]) * DMODEL + sc[q] * 4, &Asb[0][(q * 256 + tid) * 4]);
    __syncthreads();

    for (int kc = 0; kc < 8; kc++) {
        if (kc < 7) {
            const int nb = (kc + 1) & 1;
            #pragma unroll
            for (int q = 0; q < 4; q++)
                gload_lds16(pd + (row0 + rr[q]) * DMODEL + (kc + 1) * 64 + sc[q] * 4,
                            &Asb[nb][(q * 256 + tid) * 4]);
        }
        const float* Ab = &Asb[kc & 1][0];
        #pragma unroll
        for (int ks = 0; ks < 2; ks++) {
            const int ch0 = (8 * ks) | ((2 * g) ^ (c & 7));
            const int ch1 = (8 * ks) | ((2 * g + 1) ^ (c & 7));
            float4 a0 = *(const float4*)&Ab[(w * 16 + c) * 64 + ch0 * 4];
            float4 a1 = *(const float4*)&Ab[(w * 16 + c) * 64 + ch1 * 4];
            bf16x8 af;
            af[0] = (short)f2bf(a0.x); af[1] = (short)f2bf(a0.y);
            af[2] = (short)f2bf(a0.z); af[3] = (short)f2bf(a0.w);
            af[4] = (short)f2bf(a1.x); af[5] = (short)f2bf(a1.y);
            af[6] = (short)f2bf(a1.z); af[7] = (short)f2bf(a1.w);
            bf16x8 bfv = *(const bf16x8*)&edwb[c * 512 + kc * 64 + ks * 32 + g * 8];
            acc = __builtin_amdgcn_mfma_f32_16x16x32_bf16(af, bfv, acc, 0, 0, 0);
        }
        if (kc < 7) __syncthreads();
    }

    if (c < 8) {
        const float eb = edb[c];
        const int jj = j0 + w * 16 + g * 4;
        int4 mv = *(const int4*)&mask[n * LSEQ + jj];
        const float NEGINF = -__builtin_inff();
        float4 o;
        o.x = acc[0] + eb + ((!ap && mv.x) ? NEGINF : 0.0f);
        o.y = acc[1] + eb + ((!ap && mv.y) ? NEGINF : 0.0f);
        o.z = acc[2] + eb + ((!ap && mv.z) ? NEGINF : 0.0f);
        o.w = acc[3] + eb + ((!ap && mv.w) ? NEGINF : 0.0f);
        *(float4*)&biasb[(size_t)(n * 8 + c) * LL2 + (size_t)i * LSEQ + jj] = o;
    }
}

// ---------------------------------------------------------------------------
// bf16 MFMA GEMM body: 64x64 tile, 4 waves, BK=64, 4-deep pipelined staging
// (counted vmcnt + raw barriers, T3/T4), XOR-swizzled LDS.
template<int ACT, int RES, int OBF>
__device__ __forceinline__ void gemm_body(const unsigned short* __restrict__ A,
        const unsigned short* __restrict__ W, const float* __restrict__ bv,
        const float* __restrict__ Rsd, void* __restrict__ Cv,
        int Nn, int K, int m0, int n0, short* As, short* Ws) {
    const int tid  = threadIdx.x;
    const int lane = tid & 63, w = tid >> 6;
    const int wr = w >> 1, wc = w & 1;
    const int s0 = tid, s1 = 256 + tid;
    const int r0 = s0 >> 3, c0 = ((s0 & 7) ^ (r0 & 7)) << 3;
    const int r1 = s1 >> 3, c1 = ((s1 & 7) ^ (r1 & 7)) << 3;
    const unsigned short* ag0 = A + (size_t)(m0 + r0) * K + c0;
    const unsigned short* ag1 = A + (size_t)(m0 + r1) * K + c1;
    const unsigned short* wg0 = W + (size_t)(n0 + r0) * K + c0;
    const unsigned short* wg1 = W + (size_t)(n0 + r1) * K + c1;

    f32x4 acc[2][2] = {};
    const int lc = lane & 15, lr = lane >> 4;
    const int KT = K >> 6;

    // prologue: stage tiles 0..3
    #pragma unroll
    for (int t = 0; t < 4; t++) {
        const int b = t * 4096, k0 = t << 6;
        gload_lds16(ag0 + k0, &As[b + s0 * 8]);
        gload_lds16(ag1 + k0, &As[b + s1 * 8]);
        gload_lds16(wg0 + k0, &Ws[b + s0 * 8]);
        gload_lds16(wg1 + k0, &Ws[b + s1 * 8]);
    }

    for (int t = 0; t < KT; t++) {
        int rem = KT - 1 - t; if (rem > 3) rem = 3;
        wait_vmcnt(rem);
        __builtin_amdgcn_s_barrier();
        __builtin_amdgcn_sched_barrier(0);
        const int cur = (t & 3) * 4096;
        bf16x8 af[2][2], bfr[2][2];
        #pragma unroll
        for (int m = 0; m < 2; m++) {
            const int rra = wr * 32 + m * 16 + lc;
            #pragma unroll
            for (int kk = 0; kk < 2; kk++) {
                const int cc = (lr + kk * 4) ^ (rra & 7);
                af[m][kk] = *(const bf16x8*)&As[cur + rra * 64 + cc * 8];
            }
        }
        #pragma unroll
        for (int nn = 0; nn < 2; nn++) {
            const int rrb = wc * 32 + nn * 16 + lc;
            #pragma unroll
            for (int kk = 0; kk < 2; kk++) {
                const int cc = (lr + kk * 4) ^ (rrb & 7);
                bfr[nn][kk] = *(const bf16x8*)&Ws[cur + rrb * 64 + cc * 8];
            }
        }
        #pragma unroll
        for (int m = 0; m < 2; m++)
            #pragma unroll
            for (int nn = 0; nn < 2; nn++) {
                acc[m][nn] = __builtin_amdgcn_mfma_f32_16x16x32_bf16(af[m][0], bfr[nn][0], acc[m][nn], 0, 0, 0);
                acc[m][nn] = __builtin_amdgcn_mfma_f32_16x16x32_bf16(af[m][1], bfr[nn][1], acc[m][nn], 0, 0, 0);
            }
        if (t + 4 < KT) {
            __builtin_amdgcn_sched_barrier(0);
            __builtin_amdgcn_s_barrier();   // all waves done reading buf[t&3]
            const int b = cur, k0 = (t + 4) << 6;
            gload_lds16(ag0 + k0, &As[b + s0 * 8]);
            gload_lds16(ag1 + k0, &As[b + s1 * 8]);
            gload_lds16(wg0 + k0, &Ws[b + s0 * 8]);
            gload_lds16(wg1 + k0, &Ws[b + s1 * 8]);
        }
    }

    #pragma unroll
    for (int nn = 0; nn < 2; nn++) {
        int gcol = n0 + wc * 32 + nn * 16 + lc;
        float bb = bv[gcol];
        #pragma unroll
        for (int m = 0; m < 2; m++) {
            #pragma unroll
            for (int r = 0; r < 4; r++) {
                int grow = m0 + wr * 32 + m * 16 + lr * 4 + r;
                float o = acc[m][nn][r] + bb;
                if (ACT) o = o / (1.0f + expf(-o));
                if (RES) o += Rsd[(size_t)grow * Nn + gcol];
                if (OBF) ((unsigned short*)Cv)[(size_t)grow * Nn + gcol] = f2bf(o);
                else     ((float*)Cv)[(size_t)grow * Nn + gcol] = o;
            }
        }
    }
}

template<int ACT, int RES, int OBF>
__global__ __launch_bounds__(256) void mfma_gemm(const unsigned short* __restrict__ A,
                                                 const unsigned short* __restrict__ W,
                                                 const float* __restrict__ bv,
                                                 const float* __restrict__ Rsd,
                                                 void* __restrict__ Cv, int Nn, int K) {
    __shared__ short As[4 * 4096];
    __shared__ short Ws[4 * 4096];
    gemm_body<ACT, RES, OBF>(A, W, bv, Rsd, Cv, Nn, K, blockIdx.y * 64, blockIdx.x * 64, As, Ws);
}

// merged q + kv projection: grid (24, 12); bx<8 -> q, else kv
__global__ __launch_bounds__(256) void qkv_gemm(const unsigned short* __restrict__ a_in,
                                                const unsigned short* __restrict__ a_mem,
                                                const unsigned short* __restrict__ qwb,
                                                const unsigned short* __restrict__ kvwb,
                                                const float* __restrict__ qbv,
                                                const float* __restrict__ kvbv,
                                                float* __restrict__ qbuf,
                                                float* __restrict__ kvbuf) {
    __shared__ short As[4 * 4096];
    __shared__ short Ws[4 * 4096];
    const int bx = blockIdx.x;
    const unsigned short* A; const unsigned short* W; const float* bv; float* C; int Nn, n0;
    if (bx < 8) { A = a_in;  W = qwb;  bv = qbv;  C = qbuf;  Nn = DMODEL;     n0 = bx * 64; }
    else        { A = a_mem; W = kvwb; bv = kvbv; C = kvbuf; Nn = 2 * DMODEL; n0 = (bx - 8) * 64; }
    gemm_body<0, 0, 0>(A, W, bv, nullptr, C, Nn, DMODEL, blockIdx.y * 64, n0, As, Ws);
}

// ---------------------------------------------------------------------------
// scores[n,h,i,j] = 0.125 * q_i.k_j + biasb[n,h,i,j]   (mask pre-folded)
__global__ __launch_bounds__(256) void scores_kernel(const float* __restrict__ q,
                                                     const float* __restrict__ kv,
                                                     const float* __restrict__ biasb,
                                                     float* __restrict__ S) {
    const int n = blockIdx.z, h = blockIdx.y;
    const int it = blockIdx.x / 12, jt = blockIdx.x % 12;
    __shared__ float Qs[64][32];
    __shared__ float Ks[64][32];
    const int tid = threadIdx.x;
    const int r = tid >> 3, c = (tid & 7) << 3;
    {
        const float* qp = q + ((size_t)(n * LSEQ + it * 32 + r)) * DMODEL + h * HD2 + c;
        float4 q0 = *(const float4*)qp;
        float4 q1 = *(const float4*)(qp + 4);
        Qs[c+0][r]=q0.x; Qs[c+1][r]=q0.y; Qs[c+2][r]=q0.z; Qs[c+3][r]=q0.w;
        Qs[c+4][r]=q1.x; Qs[c+5][r]=q1.y; Qs[c+6][r]=q1.z; Qs[c+7][r]=q1.w;
        const float* kp = kv + ((size_t)(n * LSEQ + jt * 32 + r)) * (2 * DMODEL) + h * HD2 + c;
        float4 k0 = *(const float4*)kp;
        float4 k1 = *(const float4*)(kp + 4);
        Ks[c+0][r]=k0.x; Ks[c+1][r]=k0.y; Ks[c+2][r]=k0.z; Ks[c+3][r]=k0.w;
        Ks[c+4][r]=k1.x; Ks[c+5][r]=k1.y; Ks[c+6][r]=k1.z; Ks[c+7][r]=k1.w;
    }
    __syncthreads();
    const int tx = tid & 15, ty = tid >> 4;
    float acc[2][2] = {{0.f,0.f},{0.f,0.f}};
    #pragma unroll
    for (int k = 0; k < 64; k++) {
        float2 a  = *(const float2*)&Qs[k][ty << 1];
        float2 b2 = *(const float2*)&Ks[k][tx << 1];
        acc[0][0] = fmaf(a.x, b2.x, acc[0][0]);
        acc[0][1] = fmaf(a.x, b2.y, acc[0][1]);
        acc[1][0] = fmaf(a.y, b2.x, acc[1][0]);
        acc[1][1] = fmaf(a.y, b2.y, acc[1][1]);
    }
    #pragma unroll
    for (int i2 = 0; i2 < 2; i2++) {
        int gi = it * 32 + (ty << 1) + i2;
        #pragma unroll
        for (int j2 = 0; j2 < 2; j2++) {
            int gj = jt * 32 + (tx << 1) + j2;
            size_t idx = ((size_t)(n * 8 + h)) * LL2 + (size_t)gi * LSEQ + gj;
            S[idx] = acc[i2][j2] * 0.125f + biasb[idx];
        }
    }
}

// ---------------------------------------------------------------------------
// row softmax over 384 cols; one wave per row
__global__ __launch_bounds__(256) void softmax_kernel(float* __restrict__ S) {
    int lane = threadIdx.x & 63;
    int row  = blockIdx.x * 4 + (threadIdx.x >> 6);
    float* p = S + (size_t)row * LSEQ;
    float v[6];
    #pragma unroll
    for (int cc = 0; cc < 6; cc++) v[cc] = p[cc * 64 + lane];
    float mx = v[0];
    #pragma unroll
    for (int cc = 1; cc < 6; cc++) mx = fmaxf(mx, v[cc]);
    #pragma unroll
    for (int o = 32; o; o >>= 1) mx = fmaxf(mx, __shfl_xor(mx, o));
    float sum = 0.f;
    #pragma unroll
    for (int cc = 0; cc < 6; cc++) { v[cc] = expf(v[cc] - mx); sum += v[cc]; }
    #pragma unroll
    for (int o = 32; o; o >>= 1) sum += __shfl_xor(sum, o);
    float inv = 1.0f / sum;
    #pragma unroll
    for (int cc = 0; cc < 6; cc++) p[cc * 64 + lane] = v[cc] * inv;
}

// ---------------------------------------------------------------------------
// attn_out = P @ V  -> bf16; allpad computed in-wave
__global__ __launch_bounds__(256) void av_kernel(const float* __restrict__ S,
                                                 const float* __restrict__ kv,
                                                 const int* __restrict__ mask,
                                                 unsigned short* __restrict__ outb) {
    const int it = blockIdx.x, h = blockIdx.y, n = blockIdx.z;
    __shared__ float Ps[32][68];
    __shared__ float Vs[64][68];
    const int tid = threadIdx.x;
    const int lane = tid & 63;
    int pad = 1;
    for (int j = lane; j < LSEQ; j += 64) pad &= (mask[n * LSEQ + j] != 0) ? 1 : 0;
    unsigned long long bal = __ballot(pad != 0);
    const float zf = (bal == 0xFFFFFFFFFFFFFFFFull) ? 0.0f : 1.0f;
    const int tx = tid & 15, ty = tid >> 4;
    const int pr = tid >> 3, pc = (tid & 7) << 3;
    const int vr = tid >> 2, vc = (tid & 3) << 4;
    float acc0[4] = {0,0,0,0}, acc1[4] = {0,0,0,0};
    for (int j0 = 0; j0 < LSEQ; j0 += 64) {
        const float* sp = S + ((size_t)(n * 8 + h)) * LL2 + (size_t)(it * 32 + pr) * LSEQ + j0 + pc;
        float4 p0 = *(const float4*)sp;
        float4 p1 = *(const float4*)(sp + 4);
        *(float4*)&Ps[pr][pc]     = p0;
        *(float4*)&Ps[pr][pc + 4] = p1;
        #pragma unroll
        for (int u = 0; u < 4; u++) {
            float4 vvv = *(const float4*)&kv[((size_t)(n * LSEQ + j0 + vr)) * (2 * DMODEL)
                                             + DMODEL + h * HD2 + vc + 4 * u];
            *(float4*)&Vs[vr][vc + 4 * u] = vvv;
        }
        __syncthreads();
        #pragma unroll
        for (int j = 0; j < 64; j++) {
            float pa  = Ps[ty][j];
            float pb2 = Ps[ty + 16][j];
            float4 vv = *(const float4*)&Vs[j][tx << 2];
            acc0[0] = fmaf(pa,  vv.x, acc0[0]);
            acc0[1] = fmaf(pa,  vv.y, acc0[1]);
            acc0[2] = fmaf(pa,  vv.z, acc0[2]);
            acc0[3] = fmaf(pa,  vv.w, acc0[3]);
            acc1[0] = fmaf(pb2, vv.x, acc1[0]);
            acc1[1] = fmaf(pb2, vv.y, acc1[1]);
            acc1[2] = fmaf(pb2, vv.z, acc1[2]);
            acc1[3] = fmaf(pb2, vv.w, acc1[3]);
        }
        __syncthreads();
    }
    int i0 = it * 32;
    ushort4 o0 = {f2bf(acc0[0]*zf), f2bf(acc0[1]*zf), f2bf(acc0[2]*zf), f2bf(acc0[3]*zf)};
    ushort4 o1 = {f2bf(acc1[0]*zf), f2bf(acc1[1]*zf), f2bf(acc1[2]*zf), f2bf(acc1[3]*zf)};
    *(ushort4*)&outb[((size_t)(n * LSEQ + i0 + ty)) * DMODEL + h * HD2 + (tx << 2)]      = o0;
    *(ushort4*)&outb[((size_t)(n * LSEQ + i0 + ty + 16)) * DMODEL + h * HD2 + (tx << 2)] = o1;
}

// ---------------------------------------------------------------------------
extern "C" void kernel_launch(void* const* d_in, const int* in_sizes, int n_in,
                              void* d_out, int out_size, void* d_ws, size_t ws_size,
                              hipStream_t stream) {
    const float* x    = (const float*)d_in[0];
    const float* mem  = (const float*)d_in[1];
    const float* pd   = (const float*)d_in[2];
    const int*   mask = (const int*)d_in[3];
    const float* qw   = (const float*)d_in[4];
    const float* qbv  = (const float*)d_in[5];
    const float* kvw  = (const float*)d_in[6];
    const float* kvbv = (const float*)d_in[7];
    const float* pw   = (const float*)d_in[8];
    const float* pbv  = (const float*)d_in[9];
    const float* edw  = (const float*)d_in[10];
    const float* edb  = (const float*)d_in[11];
    const float* ln1g = (const float*)d_in[12];
    const float* ln1b = (const float*)d_in[13];
    const float* ln2g = (const float*)d_in[14];
    const float* ln2b = (const float*)d_in[15];
    const float* w1   = (const float*)d_in[16];
    const float* b1   = (const float*)d_in[17];
    const float* w2   = (const float*)d_in[18];
    const float* b2   = (const float*)d_in[19];
    const float* w3   = (const float*)d_in[20];
    const float* b3   = (const float*)d_in[21];

    float* wsf = (float*)d_ws;
    float* biasb  = wsf + 16;                            // 2359296 f32
    float* scores = biasb + (size_t)NB * NH * LL2;       // 2359296 f32
    float* qbuf   = scores + (size_t)NB * NH * LL2;      // 393216 f32
    float* kvbuf  = qbuf + (size_t)ROWS * DMODEL;        // 786432 f32
    float* x1buf  = kvbuf + (size_t)ROWS * 2 * DMODEL;   // 393216 f32
    unsigned short* a_in  = (unsigned short*)(x1buf + (size_t)ROWS * DMODEL);
    unsigned short* a_mem = a_in  + (size_t)ROWS * DMODEL;
    unsigned short* attno = a_mem + (size_t)ROWS * DMODEL;
    unsigned short* h0    = attno + (size_t)ROWS * DMODEL;
    unsigned short* h1    = h0    + (size_t)ROWS * DMODEL;
    unsigned short* h2    = h1    + (size_t)ROWS * DMLP;
    unsigned short* qwb   = h2    + (size_t)ROWS * DMLP;
    unsigned short* kvwb  = qwb   + (size_t)DMODEL * DMODEL;
    unsigned short* pwb   = kvwb  + (size_t)2 * DMODEL * DMODEL;
    unsigned short* w1b   = pwb   + (size_t)DMODEL * DMODEL;
    unsigned short* w2b   = w1b   + (size_t)DMLP * DMODEL;
    unsigned short* w3b   = w2b   + (size_t)DMLP * DMLP;
    unsigned short* edwb  = w3b   + (size_t)DMLP * DMODEL;   // 16*512 bf16

    float* outp = (float*)d_out;

    cvt_all_kernel<<<2048, 256, 0, stream>>>(qw, kvw, pw, w1, w2, w3, edw,
                                             qwb, kvwb, pwb, w1b, w2b, w3b, edwb);
    ln_kernel<<<2 * ROWS / 4, 256, 0, stream>>>(x, mem, ln1g, ln1b, a_in, a_mem);
    bias_mfma<<<NB * LL2 / 64, 256, 0, stream>>>(pd, edwb, edb, mask, biasb);

    qkv_gemm<<<dim3(24, 12), 256, 0, stream>>>(a_in, a_mem, qwb, kvwb, qbv, kvbv, qbuf, kvbuf);

    scores_kernel<<<dim3(144, NH, NB), 256, 0, stream>>>(qbuf, kvbuf, biasb, scores);
    softmax_kernel<<<(NB * NH * LSEQ) / 4, 256, 0, stream>>>(scores);
    av_kernel<<<dim3(12, NH, NB), 256, 0, stream>>>(scores, kvbuf, mask, attno);

    mfma_gemm<0,1,0><<<dim3(DMODEL/64, ROWS/64), 256, 0, stream>>>(attno, pwb, pbv, x, x1buf, DMODEL, DMODEL);
    ln_kernel<<<ROWS / 4, 256, 0, stream>>>(x1buf, x1buf, ln2g, ln2b, h0, h0);
    mfma_gemm<1,0,1><<<dim3(DMLP/64, ROWS/64), 256, 0, stream>>>(h0, w1b, b1, nullptr, h1, DMLP, DMODEL);
    mfma_gemm<1,0,1><<<dim3(DMLP/64, ROWS/64), 256, 0, stream>>>(h1, w2b, b2, nullptr, h2, DMLP, DMLP);
    mfma_gemm<0,1,0><<<dim3(DMODEL/64, ROWS/64), 256, 0, stream>>>(h2, w3b, b3, x1buf, outp, DMODEL, DMLP);
}